// Round 3
// baseline (8659.208 us; speedup 1.0000x reference)
//
#include <hip/hip_runtime.h>
#include <math.h>

// CMmodel: two sparse-addressing memory units (cosine sim -> top-10 -> softmax(relu) -> gather)
// each followed by train-mode BatchNorm + LeakyReLU.  N=32768, D=256, MEM=2048, K=10.
// fp32 scoring on vector ALU (no fp32 MFMA on CDNA4). FMA-issue floor ~218 us/unit.
//
// Geometry: 512 thr = 8 waves/block, 64 rows/block, 1 block/CU (128 KiB LDS).
// Wave w owns rows w*8..w*8+7 (A-reads are wave-uniform LDS broadcasts); lane owns
// 4 contiguous cols of each 256-col chunk (B-reads: conflict-free 16B-stride b128).
// B staged in LDS with XOR swizzle  scol = col ^ (((k>>2)&7)<<3)  -> staging writes
// are 2-way (free) instead of 8-way conflicted; reads stay conflict-free (wave-
// uniform swizzle key). Per-lane top-10 lists split across half-waves -> ~200 VGPR.

#define NROWS 32768
#define DIM   256
#define MSIZE 2048
#define TK    10
#define BM    64
#define BN    256
#define KC    32
#define NKC   8      // DIM/KC
#define NCC   8      // MSIZE/BN
#define NTHR  512
#define BNEPS 1e-5f
#define SLOPE 0.01f

union UMem {
  float ms[2][KC][BN];          // 64 KiB: double-buffered mem chunk [k][swizzled col], pre-scaled
  struct {                      // used after the GEMM phase (barrier-separated)
    float tw[8][8][TK];         // [wave][row-in-wave][e] softmax weights
    int   tx[8][8][TK];         // [wave][row-in-wave][e] gathered indices
    float cs[8][BN];            // per-wave BN column partial sums
    float cq[8][BN];            // per-wave BN column partial sumsq
  } f;
};

// gated register bubble-insert; strict > keeps earlier (lower-index) entries on ties
#define INSERT(LI, V, XI)                                               \
  do {                                                                  \
    const float v_ = (V);                                               \
    if (v_ > tv[LI][TK-1]) {                                            \
      float t_ = v_; int x_ = (XI);                                     \
      _Pragma("unroll")                                                 \
      for (int p_ = 0; p_ < TK; ++p_) {                                 \
        const bool  sw_ = (t_ > tv[LI][p_]);                            \
        const float ov_ = tv[LI][p_]; const int ox_ = ti_[LI][p_];      \
        tv[LI][p_]  = sw_ ? t_ : ov_;  ti_[LI][p_] = sw_ ? x_ : ox_;    \
        t_ = sw_ ? ov_ : t_;  x_ = sw_ ? ox_ : x_;                      \
      }                                                                 \
    }                                                                   \
  } while (0)

__global__ void __launch_bounds__(NTHR, 2) unit_kernel(
    const float* __restrict__ X,      // [NROWS][DIM]
    const float* __restrict__ M,      // [MSIZE][DIM]
    const float* __restrict__ Minv,   // [MSIZE] 1/||m_row||
    float* __restrict__ H,            // [NROWS][DIM] output (may alias X; tile staged first)
    float* __restrict__ csum, float* __restrict__ csq)  // [DIM] BN accumulators (pre-zeroed)
{
  __shared__ float xs[BM][DIM];       // 64 KiB row-major x tile, pre-scaled by 1/||x||
  __shared__ UMem u;

  const int  tid  = threadIdx.x;
  const int  w    = tid >> 6;         // wave 0..7 -> rows w*8..w*8+7
  const int  lane = tid & 63;
  const bool hi   = lane >= 32;
  const int  row0 = blockIdx.x * BM;

  // ---- stage X rows (coalesced 1KB/instr/wave), fused 1/||x|| scale ----
  #pragma unroll
  for (int p = 0; p < 8; ++p) {
    const int r = p * 8 + w;
    const float4 v = reinterpret_cast<const float4*>(X + (size_t)(row0 + r) * DIM)[lane];
    float s = v.x*v.x + v.y*v.y + v.z*v.z + v.w*v.w;
    #pragma unroll
    for (int m = 32; m >= 1; m >>= 1) s += __shfl_xor(s, m, 64);
    const float sc = 1.0f / sqrtf(s);
    const float4 o = {v.x*sc, v.y*sc, v.z*sc, v.w*sc};
    reinterpret_cast<float4*>(&xs[r][0])[lane] = o;   // 16B lane-stride: conflict-free
  }
  __syncthreads();

  // ---- per-lane top-10 for this lane's half-rows (lo: rows 0-3, hi: rows 4-7) ----
  float tv[4][TK]; int ti_[4][TK];
  #pragma unroll
  for (int i = 0; i < 4; ++i)
    #pragma unroll
    for (int p = 0; p < TK; ++p) { tv[i][p] = -INFINITY; ti_[i][p] = 0x7FFFFFFF; }

  // staging geometry (kc-invariant): kq = tid&7 selects the 4-k slice, mloc the mem row;
  // swizzled LDS col sloc = mloc ^ (kq<<3)  [2-way banked writes, permutation within 64-col group]
  const int kq = tid & 7;

  for (int cc = 0; cc < NCC; ++cc) {
    const int col0 = cc * BN;

    float mc[4]; const float4* msrc[4]; int sloc[4];
    #pragma unroll
    for (int p = 0; p < 4; ++p) {
      const int mloc = p * 64 + (tid >> 3);
      mc[p]   = Minv[col0 + mloc];
      msrc[p] = reinterpret_cast<const float4*>(M + (size_t)(col0 + mloc) * DIM) + kq;
      sloc[p] = mloc ^ (kq << 3);
    }

    float acc[8][4];
    #pragma unroll
    for (int i = 0; i < 8; ++i)
      #pragma unroll
      for (int j = 0; j < 4; ++j) acc[i][j] = 0.f;

    // prologue: stage k-chunk 0 (transposed, pre-scaled, swizzled)
    float4 g[4];
    #pragma unroll
    for (int p = 0; p < 4; ++p) g[p] = msrc[p][0];
    #pragma unroll
    for (int p = 0; p < 4; ++p) {
      u.ms[0][kq*4+0][sloc[p]] = g[p].x * mc[p];
      u.ms[0][kq*4+1][sloc[p]] = g[p].y * mc[p];
      u.ms[0][kq*4+2][sloc[p]] = g[p].z * mc[p];
      u.ms[0][kq*4+3][sloc[p]] = g[p].w * mc[p];
    }
    __syncthreads();

    for (int kc = 0; kc < NKC; ++kc) {
      const int cur = kc & 1;
      if (kc < NKC - 1) {          // issue next chunk's global loads early
        #pragma unroll
        for (int p = 0; p < 4; ++p) g[p] = msrc[p][(kc + 1) * 8];
      }
      #pragma unroll
      for (int k4 = 0; k4 < KC/4; ++k4) {
        float4 a4[8];              // 8 rows x 4 k's: wave-uniform broadcast reads
        #pragma unroll
        for (int i = 0; i < 8; ++i)
          a4[i] = *reinterpret_cast<const float4*>(&xs[w*8 + i][kc*KC + k4*4]);
        const int bcol = (lane * 4) ^ (k4 << 3);   // un-swizzle: key k>>2 == k4, wave-uniform
        #pragma unroll
        for (int j4 = 0; j4 < 4; ++j4) {
          const float4 b = *reinterpret_cast<const float4*>(&u.ms[cur][k4*4 + j4][bcol]);
          #pragma unroll
          for (int i = 0; i < 8; ++i) {
            const float a = reinterpret_cast<const float*>(&a4[i])[j4];
            acc[i][0] = fmaf(a, b.x, acc[i][0]);
            acc[i][1] = fmaf(a, b.y, acc[i][1]);
            acc[i][2] = fmaf(a, b.z, acc[i][2]);
            acc[i][3] = fmaf(a, b.w, acc[i][3]);
          }
        }
      }
      if (kc < NKC - 1) {          // write-late; one barrier per chunk
        const int nxt = cur ^ 1;
        #pragma unroll
        for (int p = 0; p < 4; ++p) {
          u.ms[nxt][kq*4+0][sloc[p]] = g[p].x * mc[p];
          u.ms[nxt][kq*4+1][sloc[p]] = g[p].y * mc[p];
          u.ms[nxt][kq*4+2][sloc[p]] = g[p].z * mc[p];
          u.ms[nxt][kq*4+3][sloc[p]] = g[p].w * mc[p];
        }
        __syncthreads();
      }
    }

    // ---- candidate exchange across half-waves, then gated top-10 insert ----
    // lo keeps rows 0-3 (gives rows 4-7); hi keeps rows 4-7 (gives rows 0-3)
    float gv[4][4];
    #pragma unroll
    for (int i = 0; i < 4; ++i)
      #pragma unroll
      for (int j = 0; j < 4; ++j) {
        const float give = hi ? acc[i][j] : acc[i+4][j];
        gv[i][j] = __shfl_xor(give, 32, 64);
      }
    const int ownc = col0 + lane * 4;
    const int gotc = col0 + (lane ^ 32) * 4;
    #pragma unroll
    for (int i = 0; i < 4; ++i) {
      #pragma unroll       // lower-column group first (tie-break: ascending index)
      for (int j = 0; j < 4; ++j) {
        const float v = hi ? gv[i][j] : acc[i][j];
        INSERT(i, v, (hi ? gotc : ownc) + j);
      }
      #pragma unroll
      for (int j = 0; j < 4; ++j) {
        const float v = hi ? acc[i+4][j] : gv[i][j];
        INSERT(i, v, (hi ? ownc : gotc) + j);
      }
    }
  }
  __syncthreads();   // all u.ms reads done -> u.f alias safe

  // ---- merge 32 lanes' lists per row (both halves in lockstep), softmax, stash to LDS ----
  #pragma unroll
  for (int li = 0; li < 4; ++li) {
    float wv[TK]; int wx[TK];
    #pragma unroll
    for (int e = 0; e < TK; ++e) {
      float hv = tv[li][0]; int hx = ti_[li][0];
      #pragma unroll
      for (int m = 1; m <= 16; m <<= 1) {     // butterfly stays within each 32-lane half
        const float ov = __shfl_xor(hv, m, 64);
        const int   ox = __shfl_xor(hx, m, 64);
        const bool take = (ov > hv) || ((ov == hv) && (ox < hx));  // jax tie-break
        hv = take ? ov : hv; hx = take ? ox : hx;
      }
      wv[e] = hv; wx[e] = hx;
      if (ti_[li][0] == hx) {                 // winning lane pops its head (indices unique)
        #pragma unroll
        for (int p = 0; p < TK-1; ++p) { tv[li][p] = tv[li][p+1]; ti_[li][p] = ti_[li][p+1]; }
        tv[li][TK-1] = -INFINITY; ti_[li][TK-1] = 0x7FFFFFFF;
      }
    }
    // softmax(relu(S)); wv[0] is the max
    const float mx = fmaxf(wv[0], 0.f);
    float we[TK]; float ssum = 0.f;
    #pragma unroll
    for (int e = 0; e < TK; ++e) { we[e] = expf(fmaxf(wv[e], 0.f) - mx); ssum += we[e]; }
    const float winv = 1.0f / ssum;
    const int r8 = (hi ? 4 : 0) + li;
    if ((lane & 31) == 0) {
      #pragma unroll
      for (int e = 0; e < TK; ++e) { u.f.tw[w][r8][e] = we[e] * winv; u.f.tx[w][r8][e] = wx[e]; }
    }
  }
  __syncthreads();

  // ---- weighted gather (full wave per row, coalesced), output write, BN partials ----
  float cS[4] = {0,0,0,0}, cQ[4] = {0,0,0,0};
  #pragma unroll
  for (int r8 = 0; r8 < 8; ++r8) {
    float h0 = 0.f, h1 = 0.f, h2 = 0.f, h3 = 0.f;
    #pragma unroll
    for (int e = 0; e < TK; ++e) {
      const float we = u.f.tw[w][r8][e];      // wave-uniform broadcast reads
      const int   xe = u.f.tx[w][r8][e];
      const float4 mv = reinterpret_cast<const float4*>(M + (size_t)xe * DIM)[lane];
      h0 = fmaf(we, mv.x, h0); h1 = fmaf(we, mv.y, h1);
      h2 = fmaf(we, mv.z, h2); h3 = fmaf(we, mv.w, h3);
    }
    const int row = row0 + w*8 + r8;
    const float4 o = {h0, h1, h2, h3};
    reinterpret_cast<float4*>(H + (size_t)row * DIM)[lane] = o;
    cS[0] += h0; cS[1] += h1; cS[2] += h2; cS[3] += h3;
    cQ[0] = fmaf(h0,h0,cQ[0]); cQ[1] = fmaf(h1,h1,cQ[1]);
    cQ[2] = fmaf(h2,h2,cQ[2]); cQ[3] = fmaf(h3,h3,cQ[3]);
  }
  {
    const float4 s4 = {cS[0],cS[1],cS[2],cS[3]}, q4 = {cQ[0],cQ[1],cQ[2],cQ[3]};
    *reinterpret_cast<float4*>(&u.f.cs[w][lane*4]) = s4;
    *reinterpret_cast<float4*>(&u.f.cq[w][lane*4]) = q4;
  }
  __syncthreads();
  // 512 threads: t<256 reduce column sums, t>=256 reduce column sumsq; 1 atomic each
  {
    const int col = tid & 255;
    float s = 0.f;
    if (tid < 256) {
      #pragma unroll
      for (int w8 = 0; w8 < 8; ++w8) s += u.f.cs[w8][col];
      atomicAdd(&csum[col], s);
    } else {
      #pragma unroll
      for (int w8 = 0; w8 < 8; ++w8) s += u.f.cq[w8][col];
      atomicAdd(&csq[col], s);
    }
  }
}

// ---------------- 1/||mem_row|| for both memories ----------------
__global__ void __launch_bounds__(256) memnorm_kernel(
    const float* __restrict__ m1, const float* __restrict__ m2,
    float* __restrict__ inv1, float* __restrict__ inv2)
{
  const int row  = blockIdx.x * 4 + (threadIdx.x >> 6);   // grid covers exactly 2*MSIZE rows
  const int lane = threadIdx.x & 63;
  const float* src = (row < MSIZE) ? m1 : m2;
  const int r = row & (MSIZE - 1);
  const float4 v = reinterpret_cast<const float4*>(src)[r * (DIM/4) + lane];
  float s = v.x*v.x + v.y*v.y + v.z*v.z + v.w*v.w;
  #pragma unroll
  for (int m = 32; m >= 1; m >>= 1) s += __shfl_xor(s, m, 64);
  if (lane == 0) ((row < MSIZE) ? inv1 : inv2)[r] = 1.0f / sqrtf(s);
}

// ---------------- BatchNorm (train-mode batch stats) + LeakyReLU, in-place safe ----------------
__global__ void __launch_bounds__(256) bn_kernel(
    const float* __restrict__ in, float* __restrict__ out,
    const float* __restrict__ cs, const float* __restrict__ cq,
    const float* __restrict__ gam, const float* __restrict__ bet)
{
  const int tid = threadIdx.x;
  const int c0  = (tid & 63) * 4;
  const int ro  = tid >> 6;
  const float invN = 1.0f / (float)NROWS;
  float sc[4], sh[4];
  #pragma unroll
  for (int j = 0; j < 4; ++j) {
    const int c = c0 + j;
    const float mean = cs[c] * invN;
    const float var  = cq[c] * invN - mean * mean;   // biased var (jnp.var / torch BN)
    const float s    = gam[c] / sqrtf(var + BNEPS);
    sc[j] = s; sh[j] = bet[c] - mean * s;
  }
  const int rbase = blockIdx.x * 128;
  #pragma unroll 4
  for (int it = 0; it < 32; ++it) {
    const int r = rbase + ro + it * 4;
    const float4 v = reinterpret_cast<const float4*>(in + (size_t)r * DIM)[tid & 63];
    float y0 = fmaf(sc[0], v.x, sh[0]);
    float y1 = fmaf(sc[1], v.y, sh[1]);
    float y2 = fmaf(sc[2], v.z, sh[2]);
    float y3 = fmaf(sc[3], v.w, sh[3]);
    y0 = y0 >= 0.f ? y0 : SLOPE * y0;
    y1 = y1 >= 0.f ? y1 : SLOPE * y1;
    y2 = y2 >= 0.f ? y2 : SLOPE * y2;
    y3 = y3 >= 0.f ? y3 : SLOPE * y3;
    const float4 o = {y0, y1, y2, y3};
    reinterpret_cast<float4*>(out + (size_t)r * DIM)[tid & 63] = o;
  }
}

extern "C" void kernel_launch(void* const* d_in, const int* in_sizes, int n_in,
                              void* d_out, int out_size, void* d_ws, size_t ws_size,
                              hipStream_t stream) {
  (void)in_sizes; (void)n_in; (void)out_size; (void)ws_size;
  const float* x    = (const float*)d_in[0];
  const float* mem1 = (const float*)d_in[1];
  const float* mem2 = (const float*)d_in[2];
  const float* g1   = (const float*)d_in[3];
  const float* b1   = (const float*)d_in[4];
  const float* g2   = (const float*)d_in[5];
  const float* b2   = (const float*)d_in[6];
  float* out = (float*)d_out;
  float* ws  = (float*)d_ws;

  // ws layout (floats): minv1[2048] | minv2[2048] | cs1[256] | cq1[256] | cs2[256] | cq2[256]
  float* minv1 = ws;
  float* minv2 = ws + 2048;
  float* cs1   = ws + 4096;
  float* cq1   = ws + 4352;
  float* cs2   = ws + 4608;
  float* cq2   = ws + 4864;

  memnorm_kernel<<<(2 * MSIZE) / 4, 256, 0, stream>>>(mem1, mem2, minv1, minv2);
  hipMemsetAsync(cs1, 0, 4 * 256 * sizeof(float), stream);   // zeros cs1,cq1,cs2,cq2 (contiguous)

  // unit 1: x -> d_out; BN1 in place
  unit_kernel<<<NROWS / BM, NTHR, 0, stream>>>(x, mem1, minv1, out, cs1, cq1);
  bn_kernel<<<NROWS / 128, 256, 0, stream>>>(out, out, cs1, cq1, g1, b1);
  // unit 2: in-place safe (each block stages its own 64 input rows before overwriting)
  unit_kernel<<<NROWS / BM, NTHR, 0, stream>>>(out, mem2, minv2, out, cs2, cq2);
  bn_kernel<<<NROWS / 128, 256, 0, stream>>>(out, out, cs2, cq2, g2, b2);
}